// Round 10
// baseline (4611.612 us; speedup 1.0000x reference)
//
#include <hip/hip_runtime.h>
#include <math.h>

typedef __attribute__((ext_vector_type(8))) short short8;
typedef __attribute__((ext_vector_type(4))) float floatx4;
typedef __attribute__((ext_vector_type(4))) unsigned uintx4;

#define NB 256
#define NH 512
#define NXP 256
#define NT 512
#define GHP 100

#define MFMA __builtin_amdgcn_mfma_f32_16x16x32_bf16

__device__ __forceinline__ unsigned short f2bf(float f) {
    union { float f; unsigned u; } x; x.f = f;
    unsigned r = x.u + 0x7FFFu + ((x.u >> 16) & 1u);
    return (unsigned short)(r >> 16);
}
__device__ __forceinline__ float sigmoidf_(float x) { return 1.0f / (1.0f + __expf(-x)); }

__device__ __forceinline__ short8 cvt8(float4 u, float4 v) {
    short8 r;
    r[0] = (short)f2bf(u.x); r[1] = (short)f2bf(u.y);
    r[2] = (short)f2bf(u.z); r[3] = (short)f2bf(u.w);
    r[4] = (short)f2bf(v.x); r[5] = (short)f2bf(v.y);
    r[6] = (short)f2bf(v.z); r[7] = (short)f2bf(v.w);
    return r;
}

// ---- device-coherent ops (sc0 sc1) — PROVEN cross-XCD (r3/r5/r7).
//      sc0-only path REFUTED (r6). Flags/drains replaced by tagged data (r10).
__device__ __forceinline__ void ldg4_nw(const void* p, uintx4& r) {
    asm volatile("global_load_dwordx4 %0, %1, off sc0 sc1"
                 : "=&v"(r) : "v"(p) : "memory");
}
__device__ __forceinline__ void st32_c(void* p, unsigned v) {
    asm volatile("global_store_dword %0, %1, off sc0 sc1" :: "v"(p), "v"(v) : "memory");
}
__device__ __forceinline__ void vm_drain() {
    asm volatile("s_waitcnt vmcnt(0)" ::: "memory");
}

__global__ void k_cvt(const float* __restrict__ src, unsigned short* __restrict__ dst, int n) {
    int i = blockIdx.x * blockDim.x + threadIdx.x;
    int stride = gridDim.x * blockDim.x;
    for (; i < n; i += stride) dst[i] = f2bf(src[i]);
}

struct KParams {
    const float *xl, *xt, *xw, *xs;
    const float *bih, *bhh, *bt;
    const unsigned short *Wihb, *Whhb, *Wthb, *Wtxb;
    unsigned *hT0, *hT1, *xT;   // tagged dwords: (epoch<<16)|bf16
    float *out;
};

// 256 blocks x 256 threads (4 waves). group = 16 blocks sharing rows m0..m0+15.
// block jc owns h-cols j0..j0+31 (gates) and x'-cols n0..n0+15.
// Exchange protocol: tagged dwords, no flags, no producer drains.
//   h_t lives in hT[t&1] with tag t (hT0 memset 0 == h_0, tag 0).
//   x'_t lives in xT with tag t+1 (memset 0 => never matches).
__global__ __launch_bounds__(256, 1)
void k_persist(KParams P)
{
    const int tid   = threadIdx.x;
    const int w     = tid >> 6;
    const int lane  = tid & 63;
    const int lr    = lane & 15;
    const int lkrow = lane >> 4;
    const int lk    = lkrow * 8;
    const int bid   = blockIdx.x;
    const int grp   = bid >> 4;
    const int jc    = bid & 15;
    const int m0    = grp * 16;
    const int j0    = jc * 32;
    const int n0    = jc * 16;

    __shared__ unsigned short sh_h[16 * 512];
    __shared__ unsigned short sh_xp[16 * 256];
    __shared__ float sh_gh[16 * GHP];
    __shared__ float sh_gx[2][16 * GHP];
    __shared__ float sh_hf[16 * 32];
    __shared__ float sh_b[6][32];
    __shared__ float sh_bt[16];

    if (tid < 32) {
        sh_b[0][tid] = P.bih[j0 + tid];
        sh_b[1][tid] = P.bih[512 + j0 + tid];
        sh_b[2][tid] = P.bih[1024 + j0 + tid];
        sh_b[3][tid] = P.bhh[j0 + tid];
        sh_b[4][tid] = P.bhh[512 + j0 + tid];
        sh_b[5][tid] = P.bhh[1024 + j0 + tid];
    }
    if (tid < 16) sh_bt[tid] = P.bt[n0 + tid];
    sh_hf[tid] = 0.f; sh_hf[tid + 256] = 0.f;

    // ---- hoist step-invariant MFMA B-operands into registers (r7-proven shape) ----
    short8 bWih[3][4];
    short8 bWhh[2][16];
    #pragma unroll
    for (int i = 0; i < 3; ++i) {
        const int u = w * 3 + i, tile = u >> 1, kh = u & 1;
        const int g = tile >> 1, sub = tile & 1;
        const unsigned short* bp =
            P.Wihb + (size_t)(g * 512 + j0 + sub * 16 + lr) * NXP + kh * 128 + lk;
        #pragma unroll
        for (int kb = 0; kb < 4; ++kb) bWih[i][kb] = *(const short8*)(bp + kb * 32);
    }
    if (w < 3) {
        #pragma unroll
        for (int sub = 0; sub < 2; ++sub) {
            const unsigned short* bp =
                P.Whhb + (size_t)(w * 512 + j0 + sub * 16 + lr) * NH + lk;
            #pragma unroll
            for (int kb = 0; kb < 16; ++kb) bWhh[sub][kb] = *(const short8*)(bp + kb * 32);
        }
    } else {
        const unsigned short* bp = P.Wthb + (size_t)(n0 + lr) * NH + lk;
        #pragma unroll
        for (int kb = 0; kb < 16; ++kb) bWhh[0][kb] = *(const short8*)(bp + kb * 32);
        const unsigned short* bx = P.Wtxb + (size_t)(n0 + lr) * 160 + lk;
        #pragma unroll
        for (int c = 0; c < 5; ++c) bWhh[1][c] = *(const short8*)(bx + c * 32);
    }
    __syncthreads();

    for (int t = 0; t < NT; ++t) {
        const unsigned* hTs = (t & 1) ? P.hT1 : P.hT0;   // h_t, tag t
        unsigned*       hTd = (t & 1) ? P.hT0 : P.hT1;   // h_{t+1}, tag t+1

        // x-input loads early (plain cached; overlap the h-poll)
        float4 xq[5][2];
        if (w == 3) {
            const size_t r = (size_t)(m0 + lr);
            #pragma unroll
            for (int c = 0; c < 5; ++c) {
                const float* pa = (c < 2) ? P.xl + (r * NT + t) * 64 + c * 32 + lk
                                : (c == 2)? P.xt + (r * NT + t) * 32 + lk
                                : (c == 3)? P.xw + (r * NT + t) * 32 + lk
                                          : P.xs + (r * NT + t) * 32 + lk;
                xq[c][0] = *(const float4*)pa;
                xq[c][1] = *(const float4*)(pa + 4);
            }
        }

        // ---- poll+stage h: tagged words carry the data ----
        {
            const int row = tid >> 4, c = (tid & 15) * 32;
            const unsigned* bp = hTs + (size_t)(m0 + row) * NH + c;
            uintx4 B[8];
            unsigned pend = 0xFFu;
            const unsigned tg = (unsigned)t;
            for (;;) {
                #pragma unroll
                for (int b = 0; b < 8; ++b)
                    if (pend & (1u << b)) ldg4_nw(bp + b * 4, B[b]);
                vm_drain();
                __builtin_amdgcn_sched_barrier(0);
                #pragma unroll
                for (int b = 0; b < 8; ++b)
                    if (pend & (1u << b)) {
                        if ((B[b][0] >> 16) == tg && (B[b][1] >> 16) == tg &&
                            (B[b][2] >> 16) == tg && (B[b][3] >> 16) == tg)
                            pend &= ~(1u << b);
                    }
                if (__ballot(pend != 0u) == 0ull) break;
                __builtin_amdgcn_s_sleep(1);
            }
            const int sw = (row & 7) * 8;
            #pragma unroll
            for (int q = 0; q < 4; ++q) {
                uintx4 pk;
                pk[0] = (B[2*q][0]   & 0xffffu) | (B[2*q][1]   << 16);
                pk[1] = (B[2*q][2]   & 0xffffu) | (B[2*q][3]   << 16);
                pk[2] = (B[2*q+1][0] & 0xffffu) | (B[2*q+1][1] << 16);
                pk[3] = (B[2*q+1][2] & 0xffffu) | (B[2*q+1][3] << 16);
                *(uintx4*)&sh_h[row * 512 + ((c + 8 * q) ^ sw)] = pk;
            }
        }
        __syncthreads();

        // ---- Phase A: gh (waves 0-2) / x' (wave 3) ----
        if (w < 3) {
            floatx4 a0 = (floatx4){0.f,0.f,0.f,0.f};
            floatx4 a1 = (floatx4){0.f,0.f,0.f,0.f};
            const int sw = (lr & 7) * 8;
            #pragma unroll
            for (int kb = 0; kb < 16; ++kb) {
                short8 a = *(const short8*)&sh_h[lr * 512 + ((kb * 32 + lk) ^ sw)];
                a0 = MFMA(a, bWhh[0][kb], a0, 0, 0, 0);
                a1 = MFMA(a, bWhh[1][kb], a1, 0, 0, 0);
            }
            #pragma unroll
            for (int rg = 0; rg < 4; ++rg) {
                const int row = lkrow * 4 + rg;
                sh_gh[row * GHP + w * 32 + lr]      = a0[rg];
                sh_gh[row * GHP + w * 32 + 16 + lr] = a1[rg];
            }
        } else {
            floatx4 acc = (floatx4){0.f,0.f,0.f,0.f};
            const int sw = (lr & 7) * 8;
            #pragma unroll
            for (int kb = 0; kb < 16; ++kb) {
                short8 a = *(const short8*)&sh_h[lr * 512 + ((kb * 32 + lk) ^ sw)];
                acc = MFMA(a, bWhh[0][kb], acc, 0, 0, 0);
            }
            #pragma unroll
            for (int c = 0; c < 5; ++c) {
                short8 a = cvt8(xq[c][0], xq[c][1]);
                acc = MFMA(a, bWhh[1][c], acc, 0, 0, 0);
            }
            // tagged x' stores: fire-and-forget, no drain, no flag
            const unsigned xtag = ((unsigned)(t + 1)) << 16;
            #pragma unroll
            for (int rg = 0; rg < 4; ++rg) {
                const int row = lkrow * 4 + rg;
                unsigned short v = f2bf(tanhf(acc[rg] + sh_bt[lr]));
                st32_c(P.xT + (size_t)(m0 + row) * NXP + n0 + lr, xtag | (unsigned)v);
            }
        }

        // ---- poll+stage x': tagged words carry the data ----
        {
            const int row = tid >> 4, c = (tid & 15) * 16;
            const unsigned* bp = P.xT + (size_t)(m0 + row) * NXP + c;
            uintx4 B[4];
            unsigned pend = 0xFu;
            const unsigned tg = (unsigned)(t + 1);
            for (;;) {
                #pragma unroll
                for (int b = 0; b < 4; ++b)
                    if (pend & (1u << b)) ldg4_nw(bp + b * 4, B[b]);
                vm_drain();
                __builtin_amdgcn_sched_barrier(0);
                #pragma unroll
                for (int b = 0; b < 4; ++b)
                    if (pend & (1u << b)) {
                        if ((B[b][0] >> 16) == tg && (B[b][1] >> 16) == tg &&
                            (B[b][2] >> 16) == tg && (B[b][3] >> 16) == tg)
                            pend &= ~(1u << b);
                    }
                if (__ballot(pend != 0u) == 0ull) break;
                __builtin_amdgcn_s_sleep(1);
            }
            const int sw = (row & 7) * 8;
            #pragma unroll
            for (int q = 0; q < 2; ++q) {
                uintx4 pk;
                pk[0] = (B[2*q][0]   & 0xffffu) | (B[2*q][1]   << 16);
                pk[1] = (B[2*q][2]   & 0xffffu) | (B[2*q][3]   << 16);
                pk[2] = (B[2*q+1][0] & 0xffffu) | (B[2*q+1][1] << 16);
                pk[3] = (B[2*q+1][2] & 0xffffu) | (B[2*q+1][3] << 16);
                *(uintx4*)&sh_xp[row * 256 + ((c + 8 * q) ^ sw)] = pk;
            }
        }
        __syncthreads();

        // ---- Phase B: gx ----
        #pragma unroll
        for (int i = 0; i < 3; ++i) {
            const int u = w * 3 + i, tile = u >> 1, kh = u & 1;
            const int g = tile >> 1, sub = tile & 1;
            floatx4 acc = (floatx4){0.f,0.f,0.f,0.f};
            const int sw = (lr & 7) * 8;
            #pragma unroll
            for (int kb = 0; kb < 4; ++kb) {
                short8 a = *(const short8*)&sh_xp[lr * 256 + ((kh * 128 + kb * 32 + lk) ^ sw)];
                acc = MFMA(a, bWih[i][kb], acc, 0, 0, 0);
            }
            #pragma unroll
            for (int rg = 0; rg < 4; ++rg) {
                const int row = lkrow * 4 + rg;
                sh_gx[kh][row * GHP + g * 32 + sub * 16 + lr] = acc[rg];
            }
        }
        __syncthreads();

        // ---- epilogue: gates + h update; tagged h stores, fire-and-forget ----
        {
            const int row = tid >> 4, jj = (tid & 15) * 2;
            float hn[2];
            #pragma unroll
            for (int jo = 0; jo < 2; ++jo) {
                const int j = jj + jo;
                float gxr = sh_gx[0][row * GHP + j]      + sh_gx[1][row * GHP + j];
                float gxz = sh_gx[0][row * GHP + 32 + j] + sh_gx[1][row * GHP + 32 + j];
                float gxn = sh_gx[0][row * GHP + 64 + j] + sh_gx[1][row * GHP + 64 + j];
                float ghr = sh_gh[row * GHP + j];
                float ghz = sh_gh[row * GHP + 32 + j];
                float ghn = sh_gh[row * GHP + 64 + j];
                float rg_ = sigmoidf_(gxr + ghr + sh_b[0][j] + sh_b[3][j]);
                float zg  = sigmoidf_(gxz + ghz + sh_b[1][j] + sh_b[4][j]);
                float ng  = tanhf(gxn + sh_b[2][j] + rg_ * (ghn + sh_b[5][j]));
                float hold = sh_hf[row * 32 + j];
                hn[jo] = (1.f - zg) * ng + zg * hold;
                sh_hf[row * 32 + j] = hn[jo];
            }
            const unsigned htag = ((unsigned)(t + 1)) << 16;
            unsigned* hp = hTd + (size_t)(m0 + row) * NH + j0 + jj;
            st32_c(hp,     htag | (unsigned)f2bf(hn[0]));
            st32_c(hp + 1, htag | (unsigned)f2bf(hn[1]));
            if (t == NT - 1) {
                float2 o; o.x = hn[0]; o.y = hn[1];
                *(float2*)&P.out[(size_t)(m0 + row) * NH + j0 + jj] = o;
            }
        }
        // no trailing sync: next-step staging barriers order LDS reuse
    }
}

extern "C" void kernel_launch(void* const* d_in, const int* in_sizes, int n_in,
                              void* d_out, int out_size, void* d_ws, size_t ws_size,
                              hipStream_t stream)
{
    (void)in_sizes; (void)n_in; (void)out_size;
    const float* xl  = (const float*)d_in[0];
    const float* xt_ = (const float*)d_in[1];
    const float* xw  = (const float*)d_in[2];
    const float* xs  = (const float*)d_in[3];
    const float* Wih = (const float*)d_in[4];
    const float* Whh = (const float*)d_in[5];
    const float* bih = (const float*)d_in[6];
    const float* bhh = (const float*)d_in[7];
    const float* Wth = (const float*)d_in[8];
    const float* Wtx = (const float*)d_in[9];
    const float* bt  = (const float*)d_in[10];

    char* p = (char*)d_ws;
    unsigned* hT0 = (unsigned*)p;               p += (size_t)NB * NH * 4;
    unsigned* hT1 = (unsigned*)p;               p += (size_t)NB * NH * 4;
    unsigned* xT  = (unsigned*)p;               p += (size_t)NB * NXP * 4;
    unsigned short* Wihb = (unsigned short*)p;  p += (size_t)1536 * 256 * 2;
    unsigned short* Whhb = (unsigned short*)p;  p += (size_t)1536 * 512 * 2;
    unsigned short* Wthb = (unsigned short*)p;  p += (size_t)256 * 512 * 2;
    unsigned short* Wtxb = (unsigned short*)p;  p += (size_t)256 * 160 * 2;
    if ((size_t)(p - (char*)d_ws) > ws_size) return;

    k_cvt<<<256, 256, 0, stream>>>(Wih, Wihb, 1536 * 256);
    k_cvt<<<256, 256, 0, stream>>>(Whh, Whhb, 1536 * 512);
    k_cvt<<<64, 256, 0, stream>>>(Wth, Wthb, 256 * 512);
    k_cvt<<<32, 256, 0, stream>>>(Wtx, Wtxb, 256 * 160);
    // CRITICAL: clear tagged buffers every launch (stale tags from a prior
    // replay would alias epochs; harness does not re-poison between replays).
    hipMemsetAsync(hT0, 0, (size_t)NB * NH * 4, stream);   // == h_0 with tag 0
    hipMemsetAsync(hT1, 0, (size_t)NB * NH * 4, stream);
    hipMemsetAsync(xT,  0, (size_t)NB * NXP * 4, stream);

    KParams P;
    P.xl = xl; P.xt = xt_; P.xw = xw; P.xs = xs;
    P.bih = bih; P.bhh = bhh; P.bt = bt;
    P.Wihb = Wihb; P.Whhb = Whhb; P.Wthb = Wthb; P.Wtxb = Wtxb;
    P.hT0 = hT0; P.hT1 = hT1; P.xT = xT;
    P.out = (float*)d_out;

    void* args[] = { &P };
    if (hipLaunchCooperativeKernel((const void*)k_persist, dim3(256), dim3(256),
                                   args, 0, stream) != hipSuccess) {
        k_persist<<<256, 256, 0, stream>>>(P);
    }
}

// Round 11
// 3544.682 us; speedup vs baseline: 1.3010x; 1.3010x over previous
//
#include <hip/hip_runtime.h>
#include <math.h>

typedef __attribute__((ext_vector_type(8))) short short8;
typedef __attribute__((ext_vector_type(4))) float floatx4;
typedef __attribute__((ext_vector_type(4))) unsigned uintx4;

#define NB 256
#define NH 512
#define NXP 256
#define NT 512
#define GHP 100

#define MFMA __builtin_amdgcn_mfma_f32_16x16x32_bf16

__device__ __forceinline__ unsigned short f2bf(float f) {
    union { float f; unsigned u; } x; x.f = f;
    unsigned r = x.u + 0x7FFFu + ((x.u >> 16) & 1u);
    return (unsigned short)(r >> 16);
}
__device__ __forceinline__ float sigmoidf_(float x) { return 1.0f / (1.0f + __expf(-x)); }

__device__ __forceinline__ short8 cvt8(float4 u, float4 v) {
    short8 r;
    r[0] = (short)f2bf(u.x); r[1] = (short)f2bf(u.y);
    r[2] = (short)f2bf(u.z); r[3] = (short)f2bf(u.w);
    r[4] = (short)f2bf(v.x); r[5] = (short)f2bf(v.y);
    r[6] = (short)f2bf(v.z); r[7] = (short)f2bf(v.w);
    return r;
}

// ---- device-coherent data ops (sc0 sc1) — PROVEN cross-XCD (r3/r5/r7).
//      sc0-only REFUTED (r6 stale reads). tagged-data exchange REFUTED (r10).
__device__ __forceinline__ void ldg4_c(const void* p0, const void* p1,
                                       const void* p2, const void* p3,
                                       uintx4& r0, uintx4& r1, uintx4& r2, uintx4& r3) {
    asm volatile(
        "global_load_dwordx4 %0, %4, off sc0 sc1\n\t"
        "global_load_dwordx4 %1, %5, off sc0 sc1\n\t"
        "global_load_dwordx4 %2, %6, off sc0 sc1\n\t"
        "global_load_dwordx4 %3, %7, off sc0 sc1\n\t"
        "s_waitcnt vmcnt(0)"
        : "=&v"(r0), "=&v"(r1), "=&v"(r2), "=&v"(r3)
        : "v"(p0), "v"(p1), "v"(p2), "v"(p3) : "memory");
}
__device__ __forceinline__ void ldg2_c(const void* p0, const void* p1,
                                       uintx4& r0, uintx4& r1) {
    asm volatile(
        "global_load_dwordx4 %0, %2, off sc0 sc1\n\t"
        "global_load_dwordx4 %1, %3, off sc0 sc1\n\t"
        "s_waitcnt vmcnt(0)"
        : "=&v"(r0), "=&v"(r1) : "v"(p0), "v"(p1) : "memory");
}
__device__ __forceinline__ void st16_c(void* p, unsigned v) {
    asm volatile("global_store_short %0, %1, off sc0 sc1" :: "v"(p), "v"(v) : "memory");
}
__device__ __forceinline__ void st32_c(void* p, unsigned v) {
    asm volatile("global_store_dword %0, %1, off sc0 sc1" :: "v"(p), "v"(v) : "memory");
}
__device__ __forceinline__ void vm_drain() {
    asm volatile("s_waitcnt vmcnt(0)" ::: "memory");
}

// ---- flag fabric: relaxed agent atomics (proven r3/r5/r7), single writer,
//      one flag per 64B line: flag i at f[i*16]. ----
__device__ __forceinline__ void flag_set(int* f, int v) {
    __hip_atomic_store(f, v, __ATOMIC_RELAXED, __HIP_MEMORY_SCOPE_AGENT);
}
__device__ __forceinline__ void poll16(const int* f, int target, int lane) {
    const int* fp = f + (lane & 15) * 16;
    for (;;) {
        int v = __hip_atomic_load(fp, __ATOMIC_RELAXED, __HIP_MEMORY_SCOPE_AGENT);
        if (__ballot(v < target) == 0ull) break;
        __builtin_amdgcn_s_sleep(1);
    }
}
__device__ __forceinline__ void poll4(const int* f, int target, int lane) {
    const int* fp = f + (lane & 3) * 16;
    for (;;) {
        int v = __hip_atomic_load(fp, __ATOMIC_RELAXED, __HIP_MEMORY_SCOPE_AGENT);
        if (__ballot(v < target) == 0ull) break;
        __builtin_amdgcn_s_sleep(1);
    }
}

__global__ void k_cvt(const float* __restrict__ src, unsigned short* __restrict__ dst, int n) {
    int i = blockIdx.x * blockDim.x + threadIdx.x;
    int stride = gridDim.x * blockDim.x;
    for (; i < n; i += stride) dst[i] = f2bf(src[i]);
}

struct KParams {
    const float *xl, *xt, *xw, *xs;
    const float *bih, *bhh, *bt;
    const unsigned short *Wihb, *Whhb, *Wthb, *Wtxb;
    unsigned short *hb0, *hb1, *xpb;
    float *out;
    int *flags;
};

// 256 blocks x 256 threads. group = 16 blocks sharing rows m0..m0+15.
// block jc owns h-cols j0..j0+31 (gates). x' production: blocks jc<4 only,
// 64 cols each (4 waves x one 16-col tile, weights in registers) -> fan-in 4.
__global__ __launch_bounds__(256, 1)
void k_persist(KParams P)
{
    const int tid   = threadIdx.x;
    const int w     = tid >> 6;
    const int lane  = tid & 63;
    const int lr    = lane & 15;
    const int lkrow = lane >> 4;
    const int lk    = lkrow * 8;
    const int bid   = blockIdx.x;
    const int grp   = bid >> 4;
    const int jc    = bid & 15;
    const int m0    = grp * 16;
    const int j0    = jc * 32;
    const bool xprod = (jc < 4);
    const int xn    = jc * 64 + w * 16;     // this wave's x' col tile (if xprod)

    // per-group flag region: 512 ints (2048 B)
    //   hfl: 16 flags at [i*16]; xfl: 4 flags at [256 + i*16]
    int* gfl = P.flags + grp * 512;
    int* hfl = gfl;
    int* xfl = gfl + 256;

    __shared__ unsigned short sh_h[16 * 512];
    __shared__ unsigned short sh_xp[16 * 256];
    __shared__ float sh_gh[16 * GHP];
    __shared__ float sh_gx[2][16 * GHP];
    __shared__ float sh_hf[16 * 32];
    __shared__ float sh_b[6][32];
    __shared__ float sh_bt[64];

    if (tid < 32) {
        sh_b[0][tid] = P.bih[j0 + tid];
        sh_b[1][tid] = P.bih[512 + j0 + tid];
        sh_b[2][tid] = P.bih[1024 + j0 + tid];
        sh_b[3][tid] = P.bhh[j0 + tid];
        sh_b[4][tid] = P.bhh[512 + j0 + tid];
        sh_b[5][tid] = P.bhh[1024 + j0 + tid];
    }
    if (xprod && tid < 64) sh_bt[tid] = P.bt[jc * 64 + tid];
    sh_hf[tid] = 0.f; sh_hf[tid + 256] = 0.f;

    // ---- hoist step-invariant MFMA B-operands into registers ----
    short8 bWih[3][4];     // gx units (all waves, all blocks)
    short8 bWhh[2][16];    // gh tiles (waves 0-2, all blocks)
    short8 bWt[21];        // x' weights: 16 Wth frags + 5 Wtx frags (producers, all waves)
    #pragma unroll
    for (int i = 0; i < 3; ++i) {
        const int u = w * 3 + i, tile = u >> 1, kh = u & 1;
        const int g = tile >> 1, sub = tile & 1;
        const unsigned short* bp =
            P.Wihb + (size_t)(g * 512 + j0 + sub * 16 + lr) * NXP + kh * 128 + lk;
        #pragma unroll
        for (int kb = 0; kb < 4; ++kb) bWih[i][kb] = *(const short8*)(bp + kb * 32);
    }
    if (w < 3) {
        #pragma unroll
        for (int sub = 0; sub < 2; ++sub) {
            const unsigned short* bp =
                P.Whhb + (size_t)(w * 512 + j0 + sub * 16 + lr) * NH + lk;
            #pragma unroll
            for (int kb = 0; kb < 16; ++kb) bWhh[sub][kb] = *(const short8*)(bp + kb * 32);
        }
    }
    if (xprod) {
        const unsigned short* bp = P.Wthb + (size_t)(xn + lr) * NH + lk;
        #pragma unroll
        for (int kb = 0; kb < 16; ++kb) bWt[kb] = *(const short8*)(bp + kb * 32);
        const unsigned short* bx = P.Wtxb + (size_t)(xn + lr) * 160 + lk;
        #pragma unroll
        for (int c = 0; c < 5; ++c) bWt[16 + c] = *(const short8*)(bx + c * 32);
    }
    __syncthreads();

    for (int t = 0; t < NT; ++t) {
        const unsigned short* hsrc = (t & 1) ? P.hb1 : P.hb0;
        unsigned short*       hdst = (t & 1) ? P.hb0 : P.hb1;

        // x-input loads early (plain cached; overlaps the h-poll)
        float4 xq[5][2];
        if (xprod) {
            const size_t r = (size_t)(m0 + lr);
            #pragma unroll
            for (int c = 0; c < 5; ++c) {
                const float* pa = (c < 2) ? P.xl + (r * NT + t) * 64 + c * 32 + lk
                                : (c == 2)? P.xt + (r * NT + t) * 32 + lk
                                : (c == 3)? P.xw + (r * NT + t) * 32 + lk
                                          : P.xs + (r * NT + t) * 32 + lk;
                xq[c][0] = *(const float4*)pa;
                xq[c][1] = *(const float4*)(pa + 4);
            }
        }

        // ---- wait for h_t (16 producer flags), stage h -> LDS ----
        poll16(hfl, t, lane);
        {
            const int row = tid >> 4, c = (tid & 15) * 32;
            const unsigned short* gp = hsrc + (size_t)(m0 + row) * NH + c;
            uintx4 r0, r1, r2, r3;
            ldg4_c(gp, gp + 8, gp + 16, gp + 24, r0, r1, r2, r3);
            const int sw = (row & 7) * 8;
            *(uintx4*)&sh_h[row * 512 + ((c +  0) ^ sw)] = r0;
            *(uintx4*)&sh_h[row * 512 + ((c +  8) ^ sw)] = r1;
            *(uintx4*)&sh_h[row * 512 + ((c + 16) ^ sw)] = r2;
            *(uintx4*)&sh_h[row * 512 + ((c + 24) ^ sw)] = r3;
        }
        __syncthreads();

        // ---- x' FIRST (producers, all 4 waves): registers only, flag ASAP ----
        if (xprod) {
            floatx4 acc = (floatx4){0.f,0.f,0.f,0.f};
            const int sw = (lr & 7) * 8;
            #pragma unroll
            for (int kb = 0; kb < 16; ++kb) {
                short8 a = *(const short8*)&sh_h[lr * 512 + ((kb * 32 + lk) ^ sw)];
                acc = MFMA(a, bWt[kb], acc, 0, 0, 0);
            }
            #pragma unroll
            for (int c = 0; c < 5; ++c) {
                short8 a = cvt8(xq[c][0], xq[c][1]);
                acc = MFMA(a, bWt[16 + c], acc, 0, 0, 0);
            }
            #pragma unroll
            for (int rg = 0; rg < 4; ++rg) {
                const int row = lkrow * 4 + rg;
                unsigned short v = f2bf(tanhf(acc[rg] + sh_bt[w * 16 + lr]));
                st16_c(P.xpb + (size_t)(m0 + row) * NXP + xn + lr, (unsigned)v);
            }
            vm_drain();
        }
        __syncthreads();                       // all 4 producer waves drained
        if (xprod && tid == 0) flag_set(xfl + jc * 16, t + 1);

        // ---- gh (waves 0-2, all blocks) — overlaps other blocks' x' wait ----
        if (w < 3) {
            floatx4 a0 = (floatx4){0.f,0.f,0.f,0.f};
            floatx4 a1 = (floatx4){0.f,0.f,0.f,0.f};
            const int sw = (lr & 7) * 8;
            #pragma unroll
            for (int kb = 0; kb < 16; ++kb) {
                short8 a = *(const short8*)&sh_h[lr * 512 + ((kb * 32 + lk) ^ sw)];
                a0 = MFMA(a, bWhh[0][kb], a0, 0, 0, 0);
                a1 = MFMA(a, bWhh[1][kb], a1, 0, 0, 0);
            }
            #pragma unroll
            for (int rg = 0; rg < 4; ++rg) {
                const int row = lkrow * 4 + rg;
                sh_gh[row * GHP + w * 32 + lr]      = a0[rg];
                sh_gh[row * GHP + w * 32 + 16 + lr] = a1[rg];
            }
        }

        // ---- wait for x'_t (4 flags), stage x' -> LDS ----
        poll4(xfl, t + 1, lane);
        {
            const int row = tid >> 4, c = (tid & 15) * 16;
            const unsigned short* gp = P.xpb + (size_t)(m0 + row) * NXP + c;
            uintx4 r0, r1;
            ldg2_c(gp, gp + 8, r0, r1);
            const int sw = (row & 7) * 8;
            *(uintx4*)&sh_xp[row * 256 + ((c + 0) ^ sw)] = r0;
            *(uintx4*)&sh_xp[row * 256 + ((c + 8) ^ sw)] = r1;
        }
        __syncthreads();

        // ---- Phase B: gx ----
        #pragma unroll
        for (int i = 0; i < 3; ++i) {
            const int u = w * 3 + i, tile = u >> 1, kh = u & 1;
            const int g = tile >> 1, sub = tile & 1;
            floatx4 acc = (floatx4){0.f,0.f,0.f,0.f};
            const int sw = (lr & 7) * 8;
            #pragma unroll
            for (int kb = 0; kb < 4; ++kb) {
                short8 a = *(const short8*)&sh_xp[lr * 256 + ((kh * 128 + kb * 32 + lk) ^ sw)];
                acc = MFMA(a, bWih[i][kb], acc, 0, 0, 0);
            }
            #pragma unroll
            for (int rg = 0; rg < 4; ++rg) {
                const int row = lkrow * 4 + rg;
                sh_gx[kh][row * GHP + g * 32 + sub * 16 + lr] = acc[rg];
            }
        }
        __syncthreads();

        // ---- epilogue: gates + h update (2 adjacent cols/thread) ----
        {
            const int row = tid >> 4, jj = (tid & 15) * 2;
            float hn[2];
            #pragma unroll
            for (int jo = 0; jo < 2; ++jo) {
                const int j = jj + jo;
                float gxr = sh_gx[0][row * GHP + j]      + sh_gx[1][row * GHP + j];
                float gxz = sh_gx[0][row * GHP + 32 + j] + sh_gx[1][row * GHP + 32 + j];
                float gxn = sh_gx[0][row * GHP + 64 + j] + sh_gx[1][row * GHP + 64 + j];
                float ghr = sh_gh[row * GHP + j];
                float ghz = sh_gh[row * GHP + 32 + j];
                float ghn = sh_gh[row * GHP + 64 + j];
                float rg_ = sigmoidf_(gxr + ghr + sh_b[0][j] + sh_b[3][j]);
                float zg  = sigmoidf_(gxz + ghz + sh_b[1][j] + sh_b[4][j]);
                float ng  = tanhf(gxn + sh_b[2][j] + rg_ * (ghn + sh_b[5][j]));
                float hold = sh_hf[row * 32 + j];
                hn[jo] = (1.f - zg) * ng + zg * hold;
                sh_hf[row * 32 + j] = hn[jo];
            }
            unsigned d = (unsigned)f2bf(hn[0]) | ((unsigned)f2bf(hn[1]) << 16);
            st32_c(hdst + (size_t)(m0 + row) * NH + j0 + jj, d);
            if (t == NT - 1) {
                float2 o; o.x = hn[0]; o.y = hn[1];
                *(float2*)&P.out[(size_t)(m0 + row) * NH + j0 + jj] = o;
            }
            vm_drain();
        }
        __syncthreads();
        if (tid == 0) flag_set(hfl + jc * 16, t + 1);
    }
}

extern "C" void kernel_launch(void* const* d_in, const int* in_sizes, int n_in,
                              void* d_out, int out_size, void* d_ws, size_t ws_size,
                              hipStream_t stream)
{
    (void)in_sizes; (void)n_in; (void)out_size;
    const float* xl  = (const float*)d_in[0];
    const float* xt_ = (const float*)d_in[1];
    const float* xw  = (const float*)d_in[2];
    const float* xs  = (const float*)d_in[3];
    const float* Wih = (const float*)d_in[4];
    const float* Whh = (const float*)d_in[5];
    const float* bih = (const float*)d_in[6];
    const float* bhh = (const float*)d_in[7];
    const float* Wth = (const float*)d_in[8];
    const float* Wtx = (const float*)d_in[9];
    const float* bt  = (const float*)d_in[10];

    char* p = (char*)d_ws;
    int* flags = (int*)p;                       p += 32768;   // 16 groups x 2048 B
    unsigned short* hb0 = (unsigned short*)p;   p += (size_t)NB * NH * 2;
    unsigned short* hb1 = (unsigned short*)p;   p += (size_t)NB * NH * 2;
    unsigned short* xpb = (unsigned short*)p;   p += (size_t)NB * NXP * 2;
    unsigned short* Wihb = (unsigned short*)p;  p += (size_t)1536 * 256 * 2;
    unsigned short* Whhb = (unsigned short*)p;  p += (size_t)1536 * 512 * 2;
    unsigned short* Wthb = (unsigned short*)p;  p += (size_t)256 * 512 * 2;
    unsigned short* Wtxb = (unsigned short*)p;  p += (size_t)256 * 160 * 2;
    if ((size_t)(p - (char*)d_ws) > ws_size) return;

    k_cvt<<<256, 256, 0, stream>>>(Wih, Wihb, 1536 * 256);
    k_cvt<<<256, 256, 0, stream>>>(Whh, Whhb, 1536 * 512);
    k_cvt<<<64, 256, 0, stream>>>(Wth, Wthb, 256 * 512);
    k_cvt<<<32, 256, 0, stream>>>(Wtx, Wtxb, 256 * 160);
    hipMemsetAsync(flags, 0, 32768, stream);
    hipMemsetAsync(hb0, 0, (size_t)NB * NH * 2, stream);

    KParams P;
    P.xl = xl; P.xt = xt_; P.xw = xw; P.xs = xs;
    P.bih = bih; P.bhh = bhh; P.bt = bt;
    P.Wihb = Wihb; P.Whhb = Whhb; P.Wthb = Wthb; P.Wtxb = Wtxb;
    P.hb0 = hb0; P.hb1 = hb1; P.xpb = xpb;
    P.out = (float*)d_out; P.flags = flags;

    void* args[] = { &P };
    if (hipLaunchCooperativeKernel((const void*)k_persist, dim3(256), dim3(256),
                                   args, 0, stream) != hipSuccess) {
        k_persist<<<256, 256, 0, stream>>>(P);
    }
}

// Round 12
// 3247.033 us; speedup vs baseline: 1.4203x; 1.0917x over previous
//
#include <hip/hip_runtime.h>
#include <math.h>

typedef __attribute__((ext_vector_type(8))) short short8;
typedef __attribute__((ext_vector_type(4))) float floatx4;
typedef __attribute__((ext_vector_type(4))) unsigned uintx4;

#define NB 256
#define NH 512
#define NXP 256
#define NT 512
#define GHP 100

#define MFMA __builtin_amdgcn_mfma_f32_16x16x32_bf16

__device__ __forceinline__ unsigned short f2bf(float f) {
    union { float f; unsigned u; } x; x.f = f;
    unsigned r = x.u + 0x7FFFu + ((x.u >> 16) & 1u);
    return (unsigned short)(r >> 16);
}
__device__ __forceinline__ float sigmoidf_(float x) { return 1.0f / (1.0f + __expf(-x)); }

__device__ __forceinline__ short8 cvt8(float4 u, float4 v) {
    short8 r;
    r[0] = (short)f2bf(u.x); r[1] = (short)f2bf(u.y);
    r[2] = (short)f2bf(u.z); r[3] = (short)f2bf(u.w);
    r[4] = (short)f2bf(v.x); r[5] = (short)f2bf(v.y);
    r[6] = (short)f2bf(v.z); r[7] = (short)f2bf(v.w);
    return r;
}

// ---- device-coherent data ops (sc0 sc1) — PROVEN cross-XCD (r3/r5/r7).
//      sc0-only REFUTED (r6). tagged-data REFUTED (r10). fan-in-4 neutral (r11).
__device__ __forceinline__ void ldg4_c(const void* p0, const void* p1,
                                       const void* p2, const void* p3,
                                       uintx4& r0, uintx4& r1, uintx4& r2, uintx4& r3) {
    asm volatile(
        "global_load_dwordx4 %0, %4, off sc0 sc1\n\t"
        "global_load_dwordx4 %1, %5, off sc0 sc1\n\t"
        "global_load_dwordx4 %2, %6, off sc0 sc1\n\t"
        "global_load_dwordx4 %3, %7, off sc0 sc1\n\t"
        "s_waitcnt vmcnt(0)"
        : "=&v"(r0), "=&v"(r1), "=&v"(r2), "=&v"(r3)
        : "v"(p0), "v"(p1), "v"(p2), "v"(p3) : "memory");
}
__device__ __forceinline__ void ldg2_c(const void* p0, const void* p1,
                                       uintx4& r0, uintx4& r1) {
    asm volatile(
        "global_load_dwordx4 %0, %2, off sc0 sc1\n\t"
        "global_load_dwordx4 %1, %3, off sc0 sc1\n\t"
        "s_waitcnt vmcnt(0)"
        : "=&v"(r0), "=&v"(r1) : "v"(p0), "v"(p1) : "memory");
}
__device__ __forceinline__ void st16_c(void* p, unsigned v) {
    asm volatile("global_store_short %0, %1, off sc0 sc1" :: "v"(p), "v"(v) : "memory");
}
__device__ __forceinline__ void st32_c(void* p, unsigned v) {
    asm volatile("global_store_dword %0, %1, off sc0 sc1" :: "v"(p), "v"(v) : "memory");
}
__device__ __forceinline__ void vm_drain() {
    asm volatile("s_waitcnt vmcnt(0)" ::: "memory");
}

// ---- flag fabric: relaxed agent atomics (proven), single writer,
//      one flag per 64B line: flag i at f[i*16]. ----
__device__ __forceinline__ void flag_set(int* f, int v) {
    __hip_atomic_store(f, v, __ATOMIC_RELAXED, __HIP_MEMORY_SCOPE_AGENT);
}
__device__ __forceinline__ void poll16(const int* f, int target, int lane) {
    const int* fp = f + (lane & 15) * 16;
    for (;;) {
        int v = __hip_atomic_load(fp, __ATOMIC_RELAXED, __HIP_MEMORY_SCOPE_AGENT);
        if (__ballot(v < target) == 0ull) break;
        __builtin_amdgcn_s_sleep(1);
    }
}

__global__ void k_cvt(const float* __restrict__ src, unsigned short* __restrict__ dst, int n) {
    int i = blockIdx.x * blockDim.x + threadIdx.x;
    int stride = gridDim.x * blockDim.x;
    for (; i < n; i += stride) dst[i] = f2bf(src[i]);
}

struct KParams {
    const float *xl, *xt, *xw, *xs;
    const float *bih, *bhh, *bt;
    const unsigned short *Wihb, *Whhb, *Wthb, *Wtxb;
    unsigned short *hb0, *hb1, *xpb;
    float *out;
    int *flags;
};

// r7 structure (best: 3.24 ms) with staging-write bank-conflict fix
// (row = tid&15 so XOR swizzle rotates banks) and h_old in registers.
__global__ __launch_bounds__(256, 1)
void k_persist(KParams P)
{
    const int tid   = threadIdx.x;
    const int w     = tid >> 6;
    const int lane  = tid & 63;
    const int lr    = lane & 15;
    const int lkrow = lane >> 4;
    const int lk    = lkrow * 8;
    const int bid   = blockIdx.x;
    const int grp   = bid >> 4;
    const int jc    = bid & 15;
    const int m0    = grp * 16;
    const int j0    = jc * 32;
    const int n0    = jc * 16;

    int* gfl = P.flags + grp * 512;
    int* hfl = gfl;
    int* xfl = gfl + 256;

    __shared__ unsigned short sh_h[16 * 512];
    __shared__ unsigned short sh_xp[16 * 256];
    __shared__ float sh_gh[16 * GHP];
    __shared__ float sh_gx[2][16 * GHP];
    __shared__ float sh_b[6][32];
    __shared__ float sh_bt[16];

    if (tid < 32) {
        sh_b[0][tid] = P.bih[j0 + tid];
        sh_b[1][tid] = P.bih[512 + j0 + tid];
        sh_b[2][tid] = P.bih[1024 + j0 + tid];
        sh_b[3][tid] = P.bhh[j0 + tid];
        sh_b[4][tid] = P.bhh[512 + j0 + tid];
        sh_b[5][tid] = P.bhh[1024 + j0 + tid];
    }
    if (tid < 16) sh_bt[tid] = P.bt[n0 + tid];

    // h_old for this thread's two epilogue outputs (same thread every step)
    float hold0 = 0.f, hold1 = 0.f;

    // ---- hoist step-invariant MFMA B-operands into registers (r7-proven) ----
    short8 bWih[3][4];
    short8 bWhh[2][16];
    #pragma unroll
    for (int i = 0; i < 3; ++i) {
        const int u = w * 3 + i, tile = u >> 1, kh = u & 1;
        const int g = tile >> 1, sub = tile & 1;
        const unsigned short* bp =
            P.Wihb + (size_t)(g * 512 + j0 + sub * 16 + lr) * NXP + kh * 128 + lk;
        #pragma unroll
        for (int kb = 0; kb < 4; ++kb) bWih[i][kb] = *(const short8*)(bp + kb * 32);
    }
    if (w < 3) {
        #pragma unroll
        for (int sub = 0; sub < 2; ++sub) {
            const unsigned short* bp =
                P.Whhb + (size_t)(w * 512 + j0 + sub * 16 + lr) * NH + lk;
            #pragma unroll
            for (int kb = 0; kb < 16; ++kb) bWhh[sub][kb] = *(const short8*)(bp + kb * 32);
        }
    } else {
        const unsigned short* bp = P.Wthb + (size_t)(n0 + lr) * NH + lk;
        #pragma unroll
        for (int kb = 0; kb < 16; ++kb) bWhh[0][kb] = *(const short8*)(bp + kb * 32);
        const unsigned short* bx = P.Wtxb + (size_t)(n0 + lr) * 160 + lk;
        #pragma unroll
        for (int c = 0; c < 5; ++c) bWhh[1][c] = *(const short8*)(bx + c * 32);
    }
    __syncthreads();

    for (int t = 0; t < NT; ++t) {
        const unsigned short* hsrc = (t & 1) ? P.hb1 : P.hb0;
        unsigned short*       hdst = (t & 1) ? P.hb0 : P.hb1;

        // x-input loads early (plain cached; overlaps the h-poll)
        float4 xq[5][2];
        if (w == 3) {
            const size_t r = (size_t)(m0 + lr);
            #pragma unroll
            for (int c = 0; c < 5; ++c) {
                const float* pa = (c < 2) ? P.xl + (r * NT + t) * 64 + c * 32 + lk
                                : (c == 2)? P.xt + (r * NT + t) * 32 + lk
                                : (c == 3)? P.xw + (r * NT + t) * 32 + lk
                                          : P.xs + (r * NT + t) * 32 + lk;
                xq[c][0] = *(const float4*)pa;
                xq[c][1] = *(const float4*)(pa + 4);
            }
        }

        // ---- wait for h_t (16 producer flags), stage h -> LDS ----
        // conflict-fixed mapping: row = tid&15 (swizzle rotates banks per row),
        // c = (tid>>4)*32 shorts (64B chunk per thread).
        poll16(hfl, t, lane);
        {
            const int row = tid & 15, c = (tid >> 4) * 32;
            const unsigned short* gp = hsrc + (size_t)(m0 + row) * NH + c;
            uintx4 r0, r1, r2, r3;
            ldg4_c(gp, gp + 8, gp + 16, gp + 24, r0, r1, r2, r3);
            const int sw = (row & 7) * 8;
            *(uintx4*)&sh_h[row * 512 + ((c +  0) ^ sw)] = r0;
            *(uintx4*)&sh_h[row * 512 + ((c +  8) ^ sw)] = r1;
            *(uintx4*)&sh_h[row * 512 + ((c + 16) ^ sw)] = r2;
            *(uintx4*)&sh_h[row * 512 + ((c + 24) ^ sw)] = r3;
        }
        __syncthreads();

        // ---- Phase A: gh (waves 0-2) / x' (wave 3) ----
        if (w < 3) {
            floatx4 a0 = (floatx4){0.f,0.f,0.f,0.f};
            floatx4 a1 = (floatx4){0.f,0.f,0.f,0.f};
            const int sw = (lr & 7) * 8;
            #pragma unroll
            for (int kb = 0; kb < 16; ++kb) {
                short8 a = *(const short8*)&sh_h[lr * 512 + ((kb * 32 + lk) ^ sw)];
                a0 = MFMA(a, bWhh[0][kb], a0, 0, 0, 0);
                a1 = MFMA(a, bWhh[1][kb], a1, 0, 0, 0);
            }
            #pragma unroll
            for (int rg = 0; rg < 4; ++rg) {
                const int row = lkrow * 4 + rg;
                sh_gh[row * GHP + w * 32 + lr]      = a0[rg];
                sh_gh[row * GHP + w * 32 + 16 + lr] = a1[rg];
            }
        } else {
            floatx4 acc = (floatx4){0.f,0.f,0.f,0.f};
            const int sw = (lr & 7) * 8;
            #pragma unroll
            for (int kb = 0; kb < 16; ++kb) {
                short8 a = *(const short8*)&sh_h[lr * 512 + ((kb * 32 + lk) ^ sw)];
                acc = MFMA(a, bWhh[0][kb], acc, 0, 0, 0);
            }
            #pragma unroll
            for (int c = 0; c < 5; ++c) {
                short8 a = cvt8(xq[c][0], xq[c][1]);
                acc = MFMA(a, bWhh[1][c], acc, 0, 0, 0);
            }
            #pragma unroll
            for (int rg = 0; rg < 4; ++rg) {
                const int row = lkrow * 4 + rg;
                unsigned short v = f2bf(tanhf(acc[rg] + sh_bt[lr]));
                st16_c(P.xpb + (size_t)(m0 + row) * NXP + n0 + lr, (unsigned)v);
            }
            vm_drain();
            if (lane == 0) flag_set(xfl + jc * 16, t + 1);
        }

        // ---- wait for x'_t, stage x' -> LDS (conflict-fixed mapping) ----
        poll16(xfl, t + 1, lane);
        {
            const int row = tid & 15, c = (tid >> 4) * 16;
            const unsigned short* gp = P.xpb + (size_t)(m0 + row) * NXP + c;
            uintx4 r0, r1;
            ldg2_c(gp, gp + 8, r0, r1);
            const int sw = (row & 7) * 8;
            *(uintx4*)&sh_xp[row * 256 + ((c + 0) ^ sw)] = r0;
            *(uintx4*)&sh_xp[row * 256 + ((c + 8) ^ sw)] = r1;
        }
        __syncthreads();

        // ---- Phase B: gx ----
        #pragma unroll
        for (int i = 0; i < 3; ++i) {
            const int u = w * 3 + i, tile = u >> 1, kh = u & 1;
            const int g = tile >> 1, sub = tile & 1;
            floatx4 acc = (floatx4){0.f,0.f,0.f,0.f};
            const int sw = (lr & 7) * 8;
            #pragma unroll
            for (int kb = 0; kb < 4; ++kb) {
                short8 a = *(const short8*)&sh_xp[lr * 256 + ((kh * 128 + kb * 32 + lk) ^ sw)];
                acc = MFMA(a, bWih[i][kb], acc, 0, 0, 0);
            }
            #pragma unroll
            for (int rg = 0; rg < 4; ++rg) {
                const int row = lkrow * 4 + rg;
                sh_gx[kh][row * GHP + g * 32 + sub * 16 + lr] = acc[rg];
            }
        }
        __syncthreads();

        // ---- epilogue: gates + h update (h_old in registers) ----
        {
            const int row = tid >> 4, jj = (tid & 15) * 2;
            float hn[2];
            #pragma unroll
            for (int jo = 0; jo < 2; ++jo) {
                const int j = jj + jo;
                float gxr = sh_gx[0][row * GHP + j]      + sh_gx[1][row * GHP + j];
                float gxz = sh_gx[0][row * GHP + 32 + j] + sh_gx[1][row * GHP + 32 + j];
                float gxn = sh_gx[0][row * GHP + 64 + j] + sh_gx[1][row * GHP + 64 + j];
                float ghr = sh_gh[row * GHP + j];
                float ghz = sh_gh[row * GHP + 32 + j];
                float ghn = sh_gh[row * GHP + 64 + j];
                float rg_ = sigmoidf_(gxr + ghr + sh_b[0][j] + sh_b[3][j]);
                float zg  = sigmoidf_(gxz + ghz + sh_b[1][j] + sh_b[4][j]);
                float ng  = tanhf(gxn + sh_b[2][j] + rg_ * (ghn + sh_b[5][j]));
                float hold = jo ? hold1 : hold0;
                hn[jo] = (1.f - zg) * ng + zg * hold;
            }
            hold0 = hn[0]; hold1 = hn[1];
            unsigned d = (unsigned)f2bf(hn[0]) | ((unsigned)f2bf(hn[1]) << 16);
            st32_c(hdst + (size_t)(m0 + row) * NH + j0 + jj, d);
            if (t == NT - 1) {
                float2 o; o.x = hn[0]; o.y = hn[1];
                *(float2*)&P.out[(size_t)(m0 + row) * NH + j0 + jj] = o;
            }
            vm_drain();
        }
        __syncthreads();
        if (tid == 0) flag_set(hfl + jc * 16, t + 1);
    }
}

extern "C" void kernel_launch(void* const* d_in, const int* in_sizes, int n_in,
                              void* d_out, int out_size, void* d_ws, size_t ws_size,
                              hipStream_t stream)
{
    (void)in_sizes; (void)n_in; (void)out_size;
    const float* xl  = (const float*)d_in[0];
    const float* xt_ = (const float*)d_in[1];
    const float* xw  = (const float*)d_in[2];
    const float* xs  = (const float*)d_in[3];
    const float* Wih = (const float*)d_in[4];
    const float* Whh = (const float*)d_in[5];
    const float* bih = (const float*)d_in[6];
    const float* bhh = (const float*)d_in[7];
    const float* Wth = (const float*)d_in[8];
    const float* Wtx = (const float*)d_in[9];
    const float* bt  = (const float*)d_in[10];

    char* p = (char*)d_ws;
    int* flags = (int*)p;                       p += 32768;   // 16 groups x 2048 B
    unsigned short* hb0 = (unsigned short*)p;   p += (size_t)NB * NH * 2;
    unsigned short* hb1 = (unsigned short*)p;   p += (size_t)NB * NH * 2;
    unsigned short* xpb = (unsigned short*)p;   p += (size_t)NB * NXP * 2;
    unsigned short* Wihb = (unsigned short*)p;  p += (size_t)1536 * 256 * 2;
    unsigned short* Whhb = (unsigned short*)p;  p += (size_t)1536 * 512 * 2;
    unsigned short* Wthb = (unsigned short*)p;  p += (size_t)256 * 512 * 2;
    unsigned short* Wtxb = (unsigned short*)p;  p += (size_t)256 * 160 * 2;
    if ((size_t)(p - (char*)d_ws) > ws_size) return;

    k_cvt<<<256, 256, 0, stream>>>(Wih, Wihb, 1536 * 256);
    k_cvt<<<256, 256, 0, stream>>>(Whh, Whhb, 1536 * 512);
    k_cvt<<<64, 256, 0, stream>>>(Wth, Wthb, 256 * 512);
    k_cvt<<<32, 256, 0, stream>>>(Wtx, Wtxb, 256 * 160);
    hipMemsetAsync(flags, 0, 32768, stream);
    hipMemsetAsync(hb0, 0, (size_t)NB * NH * 2, stream);

    KParams P;
    P.xl = xl; P.xt = xt_; P.xw = xw; P.xs = xs;
    P.bih = bih; P.bhh = bhh; P.bt = bt;
    P.Wihb = Wihb; P.Whhb = Whhb; P.Wthb = Wthb; P.Wtxb = Wtxb;
    P.hb0 = hb0; P.hb1 = hb1; P.xpb = xpb;
    P.out = (float*)d_out; P.flags = flags;

    void* args[] = { &P };
    if (hipLaunchCooperativeKernel((const void*)k_persist, dim3(256), dim3(256),
                                   args, 0, stream) != hipSuccess) {
        k_persist<<<256, 256, 0, stream>>>(P);
    }
}